// Round 3
// baseline (101.348 us; speedup 1.0000x reference)
//
#include <hip/hip_runtime.h>
#include <hip/hip_bf16.h>

// B=8, Te=512, Td=128, D_ENC=D_DEC=512, ATT=256
// ws: Whl [4096,256] f32 (scaled 2*log2e), Ul [1024,256] f32 (scaled), scores [8,128,512] f32

// ---------------------------------------------------------------------------
// Kernel 1: two fp32 GEMMs, wave-uniform-B structure.
// Block: 256 thr = 4 waves. Wave w computes 64 rows x 8 cols (lane = row).
// A staged LDS-transposed (ds_read_b32 stride-1, 2-way free); B read from
// global via wave-uniform address (L1/scalar path). LDS read = 1 b32 per
// 8 FMA.  blocks 0..511: Whl = values@W_h*SCL; 512..639: Ul = query@U_a*SCL.
// ---------------------------------------------------------------------------
__global__ __launch_bounds__(256) void gemm_pre(
    const float* __restrict__ values, const float* __restrict__ query,
    const float* __restrict__ W_h, const float* __restrict__ U_a,
    float* __restrict__ WhO, float* __restrict__ UO)
{
    __shared__ float As[16][65];   // As[k][m], bank=(k+m)%32

    const int bid = blockIdx.x;
    const float* A; const float* W; float* C;
    int mt, nt;
    if (bid < 512) { A = values; W = W_h; C = WhO; mt = bid >> 3; nt = bid & 7; }
    else { int b2 = bid - 512; A = query; W = U_a; C = UO; mt = b2 >> 3; nt = b2 & 7; }
    const int m0 = mt * 64, n0 = nt * 32;
    const int tid = threadIdx.x;
    const int lane = tid & 63;
    const int nw = __builtin_amdgcn_readfirstlane(n0 + (tid >> 6) * 8);
    const float* Bw = W + nw;

    const int sm = tid >> 2;           // staging row 0..63
    const int sk = (tid & 3) * 4;      // staging k quad

    float acc[8] = {};
    float4 av = *(const float4*)&A[(size_t)(m0 + sm) * 512 + sk];

    for (int k0 = 0; k0 < 512; k0 += 16) {
        __syncthreads();
        As[sk + 0][sm] = av.x;
        As[sk + 1][sm] = av.y;
        As[sk + 2][sm] = av.z;
        As[sk + 3][sm] = av.w;
        __syncthreads();
        if (k0 + 16 < 512)
            av = *(const float4*)&A[(size_t)(m0 + sm) * 512 + k0 + 16 + sk];
        #pragma unroll
        for (int k = 0; k < 16; ++k) {
            float a = As[k][lane];
            const float* bp = Bw + (size_t)(k0 + k) * 256;
            #pragma unroll
            for (int j = 0; j < 8; ++j)
                acc[j] = fmaf(a, bp[j], acc[j]);
        }
    }

    const float SCL = 2.8853900817779268f;  // 2*log2(e)
    float4 o0 = {acc[0] * SCL, acc[1] * SCL, acc[2] * SCL, acc[3] * SCL};
    float4 o1 = {acc[4] * SCL, acc[5] * SCL, acc[6] * SCL, acc[7] * SCL};
    float* cp = C + (size_t)(m0 + lane) * 256 + nw;
    *(float4*)cp = o0;
    *(float4*)(cp + 4) = o1;
}

// ---------------------------------------------------------------------------
// Kernel 2: scores with 2t x 2s micro-tile.  Grid 512 = 8b x 4 t-tiles x 16
// s-tiles (tile 32t x 32s), 256 thr.  Thread (ts=tid>>4, ss=tid&15) owns rows
// {ts,ts+16} x {ss,ss+16}.  score = CV - 2*sum_a V[a]*rcp(1+exp2(w+u)).
// ---------------------------------------------------------------------------
__global__ __launch_bounds__(256) void scores_k(
    const float* __restrict__ Whl, const float* __restrict__ Ul,
    const float* __restrict__ Va, float* __restrict__ scores)
{
    __shared__ float Ws[32][132];   // bank=(4r+a)%32; rows 0..15 per lane-group -> 2-way
    __shared__ float Us[32][132];
    __shared__ float Vs[256];
    __shared__ float CVs;

    const int bid = blockIdx.x;
    const int b = bid & 7;                 // XCD-pinned per batch
    const int rem = bid >> 3;              // 0..63
    const int t0 = (rem & 3) * 32;
    const int s0 = (rem >> 2) * 32;
    const int tid = threadIdx.x;

    Vs[tid] = Va[tid];
    __syncthreads();
    if (tid < 64) {
        float cv = Vs[tid] + Vs[tid + 64] + Vs[tid + 128] + Vs[tid + 192];
        #pragma unroll
        for (int off = 32; off > 0; off >>= 1)
            cv += __shfl_xor(cv, off);
        if (tid == 0) CVs = cv;
    }

    const int ts = tid >> 4;               // t row base (broadcast per 16 lanes)
    const int ss = tid & 15;               // s row base (consecutive lanes)
    const int r = tid >> 3;                // staging row 0..31
    const int c = (tid & 7) * 4;           // staging col quad

    const float* wsrc = Whl + (size_t)(b * 512 + s0 + r) * 256;
    const float* usrc = Ul + (size_t)(b * 128 + t0 + r) * 256;

    float a00 = 0.f, a01 = 0.f, a10 = 0.f, a11 = 0.f;

    for (int c0 = 0; c0 < 256; c0 += 128) {
        __syncthreads();
        #pragma unroll
        for (int j = 0; j < 4; ++j) {
            *(float4*)&Ws[r][c + 32 * j] = *(const float4*)&wsrc[c0 + c + 32 * j];
            *(float4*)&Us[r][c + 32 * j] = *(const float4*)&usrc[c0 + c + 32 * j];
        }
        __syncthreads();
        const float* w0 = Ws[ss];
        const float* w1 = Ws[ss + 16];
        const float* u0 = Us[ts];
        const float* u1 = Us[ts + 16];
        #pragma unroll 2
        for (int a = 0; a < 128; a += 4) {
            float4 wa = *(const float4*)&w0[a];
            float4 wb = *(const float4*)&w1[a];
            float4 ua = *(const float4*)&u0[a];
            float4 ub = *(const float4*)&u1[a];
            float4 v4 = *(const float4*)&Vs[c0 + a];
            const float wav[4] = {wa.x, wa.y, wa.z, wa.w};
            const float wbv[4] = {wb.x, wb.y, wb.z, wb.w};
            const float uav[4] = {ua.x, ua.y, ua.z, ua.w};
            const float ubv[4] = {ub.x, ub.y, ub.z, ub.w};
            const float vv[4] = {v4.x, v4.y, v4.z, v4.w};
            #pragma unroll
            for (int q = 0; q < 4; ++q) {
                float r00 = __builtin_amdgcn_rcpf(1.f + __builtin_amdgcn_exp2f(wav[q] + uav[q]));
                float r01 = __builtin_amdgcn_rcpf(1.f + __builtin_amdgcn_exp2f(wbv[q] + uav[q]));
                float r10 = __builtin_amdgcn_rcpf(1.f + __builtin_amdgcn_exp2f(wav[q] + ubv[q]));
                float r11 = __builtin_amdgcn_rcpf(1.f + __builtin_amdgcn_exp2f(wbv[q] + ubv[q]));
                a00 = fmaf(vv[q], r00, a00);
                a01 = fmaf(vv[q], r01, a01);
                a10 = fmaf(vv[q], r10, a10);
                a11 = fmaf(vv[q], r11, a11);
            }
        }
    }

    const float cv = CVs;
    float* sp = scores + (size_t)(b * 128 + t0 + ts) * 512 + s0 + ss;
    sp[0]   = cv - 2.f * a00;
    sp[16]  = cv - 2.f * a01;
    sp += (size_t)16 * 512;
    sp[0]   = cv - 2.f * a10;
    sp[16]  = cv - 2.f * a11;
}

// ---------------------------------------------------------------------------
// Kernel 3: softmax (no max-sub: |score| <= sum|V| ~ 7) + context.
// Grid 256 = 8b x 32 t-groups(4), 512 thr.  Ctx: thread (e4=(tid&127)*4,
// sh=tid>>7) covers s in [sh*128, sh*128+128) for all 4 t rows; LDS reduce.
// ---------------------------------------------------------------------------
__global__ __launch_bounds__(512) void softmax_ctx(
    const float* __restrict__ scores, const float* __restrict__ values,
    float* __restrict__ out_c, float* __restrict__ out_e)
{
    __shared__ float Ps[4][512];
    __shared__ float Part[3][4][512];

    const int bid = blockIdx.x;
    const int b = bid & 7;
    const int t0 = (bid >> 3) * 4;
    const int tid = threadIdx.x;

    if (tid < 256) {
        const int row = tid >> 6, lane = tid & 63;
        const float* srow = scores + (size_t)(b * 128 + t0 + row) * 512;
        float e[8]; float ssum = 0.f;
        #pragma unroll
        for (int k = 0; k < 8; ++k) {
            float v = srow[k * 64 + lane];
            e[k] = __builtin_amdgcn_exp2f(v * 1.4426950408889634f);
            ssum += e[k];
        }
        #pragma unroll
        for (int off = 32; off > 0; off >>= 1)
            ssum += __shfl_xor(ssum, off);
        const float inv = 1.0f / ssum;
        float* erow = out_e + (size_t)(b * 128 + t0 + row) * 512;
        #pragma unroll
        for (int k = 0; k < 8; ++k) {
            float p = e[k] * inv;
            Ps[row][k * 64 + lane] = p;
            erow[k * 64 + lane] = p;
        }
    }
    __syncthreads();

    const int e4 = (tid & 127) * 4;
    const int sh = tid >> 7;               // 0..3
    const int sb = sh * 128;
    const float* vb = values + (size_t)b * 262144;

    float4 a0 = {0,0,0,0}, a1 = {0,0,0,0}, a2 = {0,0,0,0}, a3 = {0,0,0,0};
    #pragma unroll 2
    for (int s2 = 0; s2 < 128; s2 += 4) {
        float4 q0 = *(const float4*)&Ps[0][sb + s2];
        float4 q1 = *(const float4*)&Ps[1][sb + s2];
        float4 q2 = *(const float4*)&Ps[2][sb + s2];
        float4 q3 = *(const float4*)&Ps[3][sb + s2];
        const float q0v[4] = {q0.x, q0.y, q0.z, q0.w};
        const float q1v[4] = {q1.x, q1.y, q1.z, q1.w};
        const float q2v[4] = {q2.x, q2.y, q2.z, q2.w};
        const float q3v[4] = {q3.x, q3.y, q3.z, q3.w};
        #pragma unroll
        for (int j = 0; j < 4; ++j) {
            float4 v4 = *(const float4*)&vb[(size_t)(sb + s2 + j) * 512 + e4];
            a0.x = fmaf(q0v[j], v4.x, a0.x); a0.y = fmaf(q0v[j], v4.y, a0.y);
            a0.z = fmaf(q0v[j], v4.z, a0.z); a0.w = fmaf(q0v[j], v4.w, a0.w);
            a1.x = fmaf(q1v[j], v4.x, a1.x); a1.y = fmaf(q1v[j], v4.y, a1.y);
            a1.z = fmaf(q1v[j], v4.z, a1.z); a1.w = fmaf(q1v[j], v4.w, a1.w);
            a2.x = fmaf(q2v[j], v4.x, a2.x); a2.y = fmaf(q2v[j], v4.y, a2.y);
            a2.z = fmaf(q2v[j], v4.z, a2.z); a2.w = fmaf(q2v[j], v4.w, a2.w);
            a3.x = fmaf(q3v[j], v4.x, a3.x); a3.y = fmaf(q3v[j], v4.y, a3.y);
            a3.z = fmaf(q3v[j], v4.z, a3.z); a3.w = fmaf(q3v[j], v4.w, a3.w);
        }
    }

    if (sh) {
        *(float4*)&Part[sh - 1][0][e4] = a0;
        *(float4*)&Part[sh - 1][1][e4] = a1;
        *(float4*)&Part[sh - 1][2][e4] = a2;
        *(float4*)&Part[sh - 1][3][e4] = a3;
    }
    __syncthreads();
    if (!sh) {
        #pragma unroll
        for (int rrow = 0; rrow < 4; ++rrow) {
            float4 acc = (rrow == 0) ? a0 : (rrow == 1) ? a1 : (rrow == 2) ? a2 : a3;
            #pragma unroll
            for (int g = 0; g < 3; ++g) {
                float4 p4 = *(const float4*)&Part[g][rrow][e4];
                acc.x += p4.x; acc.y += p4.y; acc.z += p4.z; acc.w += p4.w;
            }
            *(float4*)&out_c[(size_t)(b * 128 + t0 + rrow) * 512 + e4] = acc;
        }
    }
}

// ---------------------------------------------------------------------------
extern "C" void kernel_launch(void* const* d_in, const int* in_sizes, int n_in,
                              void* d_out, int out_size, void* d_ws, size_t ws_size,
                              hipStream_t stream) {
    const float* values = (const float*)d_in[0];  // [8,512,512]
    const float* query  = (const float*)d_in[1];  // [8,128,512]
    const float* W_h    = (const float*)d_in[2];  // [512,256]
    const float* U_a    = (const float*)d_in[3];  // [512,256]
    const float* V_a    = (const float*)d_in[4];  // [1,256]

    float* ws     = (float*)d_ws;
    float* Whl    = ws;                        // 4096*256
    float* Ul     = ws + 4096 * 256;           // 1024*256
    float* scores = Ul + 1024 * 256;           // 8*128*512

    float* out_c = (float*)d_out;              // [8,128,512]
    float* out_e = out_c + 8 * 128 * 512;      // [8,128,512]

    hipLaunchKernelGGL(gemm_pre, dim3(640), dim3(256), 0, stream,
                       values, query, W_h, U_a, Whl, Ul);
    hipLaunchKernelGGL(scores_k, dim3(512), dim3(256), 0, stream,
                       Whl, Ul, V_a, scores);
    hipLaunchKernelGGL(softmax_ctx, dim3(256), dim3(512), 0, stream,
                       scores, values, out_c, out_e);
}

// Round 4
// 89.141 us; speedup vs baseline: 1.1369x; 1.1369x over previous
//
#include <hip/hip_runtime.h>
#include <hip/hip_bf16.h>

// B=8, Te=512, Td=128, D_ENC=D_DEC=512, ATT=256
// ws: Whl [4096,256] f32 (scaled 2*log2e), Ul [1024,256] f32 (scaled),
//     scores [8,128,512] f32, WtHi/WtLo [2][256][512] bf16 planes (W^T hi/lo)

typedef __attribute__((ext_vector_type(8))) short bf16x8;
typedef __attribute__((ext_vector_type(4))) float f32x4;
typedef __attribute__((ext_vector_type(8))) short short8;

__device__ inline void f32_to_bf16_pair(float x, short& h, short& l) {
    unsigned u = __builtin_bit_cast(unsigned, x);
    unsigned r = u + 0x7FFFu + ((u >> 16) & 1u);          // RNE to bf16
    h = (short)(r >> 16);
    float xh = __builtin_bit_cast(float, r & 0xFFFF0000u); // hi as f32
    float xl = x - xh;
    unsigned u2 = __builtin_bit_cast(unsigned, xl);
    unsigned r2 = u2 + 0x7FFFu + ((u2 >> 16) & 1u);
    l = (short)(r2 >> 16);
}

// ---------------------------------------------------------------------------
// Kernel 0: transpose + convert W_h, U_a -> WtHi/WtLo [mat][n=256][k=512] bf16.
// Grid 64 = 2 mat x 8 kt x 4 nt, 256 thr, 64x64 tile via LDS.
// ---------------------------------------------------------------------------
__global__ __launch_bounds__(256) void prep_w(
    const float* __restrict__ W_h, const float* __restrict__ U_a,
    short* __restrict__ WtHi, short* __restrict__ WtLo)
{
    __shared__ float T[64][65];
    const int bid = blockIdx.x;
    const int mat = bid >> 5, kt = (bid >> 2) & 7, nt = bid & 3;
    const float* W = mat ? U_a : W_h;
    const int tid = threadIdx.x;

    {   // stage 64k x 64n f32 tile, coalesced
        const int k = tid >> 2, cq = (tid & 3) * 16;
        const float* src = W + (size_t)(kt * 64 + k) * 256 + nt * 64 + cq;
        #pragma unroll
        for (int q = 0; q < 4; ++q)
            *(float4*)&T[k][cq + q * 4] = *(const float4*)&src[q * 4];
    }
    __syncthreads();
    {   // read column n, write k-contiguous hi/lo planes
        const int n = tid >> 2, kq = (tid & 3) * 16;
        short8 hv[2], lv[2];
        #pragma unroll
        for (int i = 0; i < 16; ++i) {
            short h, l;
            f32_to_bf16_pair(T[kq + i][n], h, l);
            hv[i >> 3][i & 7] = h;
            lv[i >> 3][i & 7] = l;
        }
        size_t off = (size_t)mat * 131072 + (size_t)(nt * 64 + n) * 512 + kt * 64 + kq;
        *(short8*)(WtHi + off) = hv[0];
        *(short8*)(WtHi + off + 8) = hv[1];
        *(short8*)(WtLo + off) = lv[0];
        *(short8*)(WtLo + off + 8) = lv[1];
    }
}

// ---------------------------------------------------------------------------
// Kernel 1: MFMA split-bf16 GEMM.  C[5120,256] = A[5120,512] @ W[512,256] * SCL
// rows 0..4095: values @ W_h -> Whl;  rows 4096..5119: query @ U_a -> Ul.
// Grid 640 = 160 mt(32 rows) x 4 nt(64 cols), 128 thr = 2 waves.
// Wave: 16 rows x 64 cols. A frag register-direct (row-major k-contig);
// B frag register-direct from pre-transposed Wt planes. 3-pass hi/lo split.
// No LDS. C/D layout (m89-verified): col=lane&15, row=(lane>>4)*4+reg.
// ---------------------------------------------------------------------------
__global__ __launch_bounds__(128) void gemm_mfma(
    const float* __restrict__ values, const float* __restrict__ query,
    const short* __restrict__ WtHi, const short* __restrict__ WtLo,
    float* __restrict__ WhO, float* __restrict__ UO)
{
    const int bid = blockIdx.x;
    const int mt = bid >> 2, nt = bid & 3;
    const float* A; const short *BH, *BL; float* C; int m0;
    if (mt < 128) { A = values; BH = WtHi; BL = WtLo; C = WhO; m0 = mt * 32; }
    else { A = query; BH = WtHi + 131072; BL = WtLo + 131072; C = UO; m0 = (mt - 128) * 32; }

    const int tid = threadIdx.x;
    const int w = tid >> 6, l = tid & 63;
    const int lr = l & 15, lg = l >> 4;

    const float* arow = A + (size_t)(m0 + w * 16 + lr) * 512 + lg * 8;
    const short* bh = BH + (size_t)(nt * 64 + lr) * 512 + lg * 8;
    const short* bl = BL + (size_t)(nt * 64 + lr) * 512 + lg * 8;

    f32x4 acc[4];
    #pragma unroll
    for (int nc = 0; nc < 4; ++nc) acc[nc] = (f32x4){0.f, 0.f, 0.f, 0.f};

    for (int k0 = 0; k0 < 512; k0 += 32) {
        float4 a0 = *(const float4*)(arow + k0);
        float4 a1 = *(const float4*)(arow + k0 + 4);
        float xs[8] = {a0.x, a0.y, a0.z, a0.w, a1.x, a1.y, a1.z, a1.w};
        bf16x8 ah, al;
        #pragma unroll
        for (int j = 0; j < 8; ++j) {
            short h, lo2;
            f32_to_bf16_pair(xs[j], h, lo2);
            ah[j] = h; al[j] = lo2;
        }
        #pragma unroll
        for (int nc = 0; nc < 4; ++nc) {
            bf16x8 bhv = *(const bf16x8*)(bh + (size_t)nc * 8192 + k0);
            bf16x8 blv = *(const bf16x8*)(bl + (size_t)nc * 8192 + k0);
            acc[nc] = __builtin_amdgcn_mfma_f32_16x16x32_bf16(ah, bhv, acc[nc], 0, 0, 0);
            acc[nc] = __builtin_amdgcn_mfma_f32_16x16x32_bf16(al, bhv, acc[nc], 0, 0, 0);
            acc[nc] = __builtin_amdgcn_mfma_f32_16x16x32_bf16(ah, blv, acc[nc], 0, 0, 0);
        }
    }

    const float SCL = 2.8853900817779268f;  // 2*log2(e)
    float* cp = C + (size_t)(m0 + w * 16 + lg * 4) * 256 + nt * 64 + lr;
    #pragma unroll
    for (int nc = 0; nc < 4; ++nc)
        #pragma unroll
        for (int r = 0; r < 4; ++r)
            cp[(size_t)r * 256 + nc * 16] = acc[nc][r] * SCL;
}

// ---------------------------------------------------------------------------
// Kernel 2: scores with 2t x 2s micro-tile.  Grid 512 = 8b x 4 t-tiles x 16
// s-tiles (tile 32t x 32s), 256 thr.  score = CV - 2*sum_a V[a]*rcp(1+exp2(w+u)).
// ---------------------------------------------------------------------------
__global__ __launch_bounds__(256) void scores_k(
    const float* __restrict__ Whl, const float* __restrict__ Ul,
    const float* __restrict__ Va, float* __restrict__ scores)
{
    __shared__ float Ws[32][132];
    __shared__ float Us[32][132];
    __shared__ float Vs[256];
    __shared__ float CVs;

    const int bid = blockIdx.x;
    const int b = bid & 7;
    const int rem = bid >> 3;
    const int t0 = (rem & 3) * 32;
    const int s0 = (rem >> 2) * 32;
    const int tid = threadIdx.x;

    Vs[tid] = Va[tid];
    __syncthreads();
    if (tid < 64) {
        float cv = Vs[tid] + Vs[tid + 64] + Vs[tid + 128] + Vs[tid + 192];
        #pragma unroll
        for (int off = 32; off > 0; off >>= 1)
            cv += __shfl_xor(cv, off);
        if (tid == 0) CVs = cv;
    }

    const int ts = tid >> 4;
    const int ss = tid & 15;
    const int r = tid >> 3;
    const int c = (tid & 7) * 4;

    const float* wsrc = Whl + (size_t)(b * 512 + s0 + r) * 256;
    const float* usrc = Ul + (size_t)(b * 128 + t0 + r) * 256;

    float a00 = 0.f, a01 = 0.f, a10 = 0.f, a11 = 0.f;

    for (int c0 = 0; c0 < 256; c0 += 128) {
        __syncthreads();
        #pragma unroll
        for (int j = 0; j < 4; ++j) {
            *(float4*)&Ws[r][c + 32 * j] = *(const float4*)&wsrc[c0 + c + 32 * j];
            *(float4*)&Us[r][c + 32 * j] = *(const float4*)&usrc[c0 + c + 32 * j];
        }
        __syncthreads();
        const float* w0 = Ws[ss];
        const float* w1 = Ws[ss + 16];
        const float* u0 = Us[ts];
        const float* u1 = Us[ts + 16];
        #pragma unroll 2
        for (int a = 0; a < 128; a += 4) {
            float4 wa = *(const float4*)&w0[a];
            float4 wb = *(const float4*)&w1[a];
            float4 ua = *(const float4*)&u0[a];
            float4 ub = *(const float4*)&u1[a];
            float4 v4 = *(const float4*)&Vs[c0 + a];
            const float wav[4] = {wa.x, wa.y, wa.z, wa.w};
            const float wbv[4] = {wb.x, wb.y, wb.z, wb.w};
            const float uav[4] = {ua.x, ua.y, ua.z, ua.w};
            const float ubv[4] = {ub.x, ub.y, ub.z, ub.w};
            const float vv[4] = {v4.x, v4.y, v4.z, v4.w};
            #pragma unroll
            for (int q = 0; q < 4; ++q) {
                float r00 = __builtin_amdgcn_rcpf(1.f + __builtin_amdgcn_exp2f(wav[q] + uav[q]));
                float r01 = __builtin_amdgcn_rcpf(1.f + __builtin_amdgcn_exp2f(wbv[q] + uav[q]));
                float r10 = __builtin_amdgcn_rcpf(1.f + __builtin_amdgcn_exp2f(wav[q] + ubv[q]));
                float r11 = __builtin_amdgcn_rcpf(1.f + __builtin_amdgcn_exp2f(wbv[q] + ubv[q]));
                a00 = fmaf(vv[q], r00, a00);
                a01 = fmaf(vv[q], r01, a01);
                a10 = fmaf(vv[q], r10, a10);
                a11 = fmaf(vv[q], r11, a11);
            }
        }
    }

    const float cv = CVs;
    float* sp = scores + (size_t)(b * 128 + t0 + ts) * 512 + s0 + ss;
    sp[0]  = cv - 2.f * a00;
    sp[16] = cv - 2.f * a01;
    sp += (size_t)16 * 512;
    sp[0]  = cv - 2.f * a10;
    sp[16] = cv - 2.f * a11;
}

// ---------------------------------------------------------------------------
// Kernel 3: softmax (no max-sub: |score| <= sum|V| ~ 7) + context.
// Grid 256 = 8b x 32 t-groups(4), 512 thr.
// ---------------------------------------------------------------------------
__global__ __launch_bounds__(512) void softmax_ctx(
    const float* __restrict__ scores, const float* __restrict__ values,
    float* __restrict__ out_c, float* __restrict__ out_e)
{
    __shared__ float Ps[4][512];
    __shared__ float Part[3][4][512];

    const int bid = blockIdx.x;
    const int b = bid & 7;
    const int t0 = (bid >> 3) * 4;
    const int tid = threadIdx.x;

    if (tid < 256) {
        const int row = tid >> 6, lane = tid & 63;
        const float* srow = scores + (size_t)(b * 128 + t0 + row) * 512;
        float e[8]; float ssum = 0.f;
        #pragma unroll
        for (int k = 0; k < 8; ++k) {
            float v = srow[k * 64 + lane];
            e[k] = __builtin_amdgcn_exp2f(v * 1.4426950408889634f);
            ssum += e[k];
        }
        #pragma unroll
        for (int off = 32; off > 0; off >>= 1)
            ssum += __shfl_xor(ssum, off);
        const float inv = 1.0f / ssum;
        float* erow = out_e + (size_t)(b * 128 + t0 + row) * 512;
        #pragma unroll
        for (int k = 0; k < 8; ++k) {
            float p = e[k] * inv;
            Ps[row][k * 64 + lane] = p;
            erow[k * 64 + lane] = p;
        }
    }
    __syncthreads();

    const int e4 = (tid & 127) * 4;
    const int sh = tid >> 7;
    const int sb = sh * 128;
    const float* vb = values + (size_t)b * 262144;

    float4 a0 = {0,0,0,0}, a1 = {0,0,0,0}, a2 = {0,0,0,0}, a3 = {0,0,0,0};
    #pragma unroll 2
    for (int s2 = 0; s2 < 128; s2 += 4) {
        float4 q0 = *(const float4*)&Ps[0][sb + s2];
        float4 q1 = *(const float4*)&Ps[1][sb + s2];
        float4 q2 = *(const float4*)&Ps[2][sb + s2];
        float4 q3 = *(const float4*)&Ps[3][sb + s2];
        const float q0v[4] = {q0.x, q0.y, q0.z, q0.w};
        const float q1v[4] = {q1.x, q1.y, q1.z, q1.w};
        const float q2v[4] = {q2.x, q2.y, q2.z, q2.w};
        const float q3v[4] = {q3.x, q3.y, q3.z, q3.w};
        #pragma unroll
        for (int j = 0; j < 4; ++j) {
            float4 v4 = *(const float4*)&vb[(size_t)(sb + s2 + j) * 512 + e4];
            a0.x = fmaf(q0v[j], v4.x, a0.x); a0.y = fmaf(q0v[j], v4.y, a0.y);
            a0.z = fmaf(q0v[j], v4.z, a0.z); a0.w = fmaf(q0v[j], v4.w, a0.w);
            a1.x = fmaf(q1v[j], v4.x, a1.x); a1.y = fmaf(q1v[j], v4.y, a1.y);
            a1.z = fmaf(q1v[j], v4.z, a1.z); a1.w = fmaf(q1v[j], v4.w, a1.w);
            a2.x = fmaf(q2v[j], v4.x, a2.x); a2.y = fmaf(q2v[j], v4.y, a2.y);
            a2.z = fmaf(q2v[j], v4.z, a2.z); a2.w = fmaf(q2v[j], v4.w, a2.w);
            a3.x = fmaf(q3v[j], v4.x, a3.x); a3.y = fmaf(q3v[j], v4.y, a3.y);
            a3.z = fmaf(q3v[j], v4.z, a3.z); a3.w = fmaf(q3v[j], v4.w, a3.w);
        }
    }

    if (sh) {
        *(float4*)&Part[sh - 1][0][e4] = a0;
        *(float4*)&Part[sh - 1][1][e4] = a1;
        *(float4*)&Part[sh - 1][2][e4] = a2;
        *(float4*)&Part[sh - 1][3][e4] = a3;
    }
    __syncthreads();
    if (!sh) {
        #pragma unroll
        for (int rrow = 0; rrow < 4; ++rrow) {
            float4 acc = (rrow == 0) ? a0 : (rrow == 1) ? a1 : (rrow == 2) ? a2 : a3;
            #pragma unroll
            for (int g = 0; g < 3; ++g) {
                float4 p4 = *(const float4*)&Part[g][rrow][e4];
                acc.x += p4.x; acc.y += p4.y; acc.z += p4.z; acc.w += p4.w;
            }
            *(float4*)&out_c[(size_t)(b * 128 + t0 + rrow) * 512 + e4] = acc;
        }
    }
}

// ---------------------------------------------------------------------------
extern "C" void kernel_launch(void* const* d_in, const int* in_sizes, int n_in,
                              void* d_out, int out_size, void* d_ws, size_t ws_size,
                              hipStream_t stream) {
    const float* values = (const float*)d_in[0];  // [8,512,512]
    const float* query  = (const float*)d_in[1];  // [8,128,512]
    const float* W_h    = (const float*)d_in[2];  // [512,256]
    const float* U_a    = (const float*)d_in[3];  // [512,256]
    const float* V_a    = (const float*)d_in[4];  // [1,256]

    float* ws     = (float*)d_ws;
    float* Whl    = ws;                            // 4096*256 f32
    float* Ul     = ws + 1048576;                  // 1024*256 f32
    float* scores = ws + 1310720;                  // 8*128*512 f32
    short* WtHi   = (short*)(ws + 1835008);        // 2*256*512 bf16
    short* WtLo   = WtHi + 262144;                 // 2*256*512 bf16

    float* out_c = (float*)d_out;                  // [8,128,512]
    float* out_e = out_c + 8 * 128 * 512;          // [8,128,512]

    hipLaunchKernelGGL(prep_w, dim3(64), dim3(256), 0, stream,
                       W_h, U_a, WtHi, WtLo);
    hipLaunchKernelGGL(gemm_mfma, dim3(640), dim3(128), 0, stream,
                       values, query, WtHi, WtLo, Whl, Ul);
    hipLaunchKernelGGL(scores_k, dim3(512), dim3(256), 0, stream,
                       Whl, Ul, V_a, scores);
    hipLaunchKernelGGL(softmax_ctx, dim3(256), dim3(512), 0, stream,
                       scores, values, out_c, out_e);
}

// Round 5
// 79.954 us; speedup vs baseline: 1.2676x; 1.1149x over previous
//
#include <hip/hip_runtime.h>
#include <hip/hip_bf16.h>

// B=8, Te=512, Td=128, D_ENC=D_DEC=512, ATT=256
// ws: Whl [4096,256] f32 (scaled 2*log2e), Ul [1024,256] f32 (scaled),
//     scoresP [4][8*128*512] f32 partial sums, WtHi/WtLo [2][256][512] bf16

typedef __attribute__((ext_vector_type(8))) short bf16x8;
typedef __attribute__((ext_vector_type(4))) float f32x4;
typedef __attribute__((ext_vector_type(8))) short short8;

__device__ inline void f32_to_bf16_pair(float x, short& h, short& l) {
    unsigned u = __builtin_bit_cast(unsigned, x);
    unsigned r = u + 0x7FFFu + ((u >> 16) & 1u);           // RNE to bf16
    h = (short)(r >> 16);
    float xh = __builtin_bit_cast(float, r & 0xFFFF0000u);
    float xl = x - xh;
    unsigned u2 = __builtin_bit_cast(unsigned, xl);
    unsigned r2 = u2 + 0x7FFFu + ((u2 >> 16) & 1u);
    l = (short)(r2 >> 16);
}

// ---------------------------------------------------------------------------
// Kernel 0: transpose + convert W_h, U_a -> WtHi/WtLo [mat][n=256][k=512] bf16.
// ---------------------------------------------------------------------------
__global__ __launch_bounds__(256) void prep_w(
    const float* __restrict__ W_h, const float* __restrict__ U_a,
    short* __restrict__ WtHi, short* __restrict__ WtLo)
{
    __shared__ float T[64][65];
    const int bid = blockIdx.x;
    const int mat = bid >> 5, kt = (bid >> 2) & 7, nt = bid & 3;
    const float* W = mat ? U_a : W_h;
    const int tid = threadIdx.x;

    {
        const int k = tid >> 2, cq = (tid & 3) * 16;
        const float* src = W + (size_t)(kt * 64 + k) * 256 + nt * 64 + cq;
        #pragma unroll
        for (int q = 0; q < 4; ++q)
            *(float4*)&T[k][cq + q * 4] = *(const float4*)&src[q * 4];
    }
    __syncthreads();
    {
        const int n = tid >> 2, kq = (tid & 3) * 16;
        short8 hv[2], lv[2];
        #pragma unroll
        for (int i = 0; i < 16; ++i) {
            short h, l;
            f32_to_bf16_pair(T[kq + i][n], h, l);
            hv[i >> 3][i & 7] = h;
            lv[i >> 3][i & 7] = l;
        }
        size_t off = (size_t)mat * 131072 + (size_t)(nt * 64 + n) * 512 + kt * 64 + kq;
        *(short8*)(WtHi + off) = hv[0];
        *(short8*)(WtHi + off + 8) = hv[1];
        *(short8*)(WtLo + off) = lv[0];
        *(short8*)(WtLo + off + 8) = lv[1];
    }
}

// ---------------------------------------------------------------------------
// Kernel 1: MFMA split-bf16 GEMM (3-pass).  rows 0..4095: values@W_h -> Whl;
// rows 4096..5119: query@U_a -> Ul.  Grid 640 = 160 mt x 4 nt, 128 thr.
// ---------------------------------------------------------------------------
__global__ __launch_bounds__(128) void gemm_mfma(
    const float* __restrict__ values, const float* __restrict__ query,
    const short* __restrict__ WtHi, const short* __restrict__ WtLo,
    float* __restrict__ WhO, float* __restrict__ UO)
{
    const int bid = blockIdx.x;
    const int mt = bid >> 2, nt = bid & 3;
    const float* A; const short *BH, *BL; float* C; int m0;
    if (mt < 128) { A = values; BH = WtHi; BL = WtLo; C = WhO; m0 = mt * 32; }
    else { A = query; BH = WtHi + 131072; BL = WtLo + 131072; C = UO; m0 = (mt - 128) * 32; }

    const int tid = threadIdx.x;
    const int w = tid >> 6, l = tid & 63;
    const int lr = l & 15, lg = l >> 4;

    const float* arow = A + (size_t)(m0 + w * 16 + lr) * 512 + lg * 8;
    const short* bh = BH + (size_t)(nt * 64 + lr) * 512 + lg * 8;
    const short* bl = BL + (size_t)(nt * 64 + lr) * 512 + lg * 8;

    f32x4 acc[4];
    #pragma unroll
    for (int nc = 0; nc < 4; ++nc) acc[nc] = (f32x4){0.f, 0.f, 0.f, 0.f};

    for (int k0 = 0; k0 < 512; k0 += 32) {
        float4 a0 = *(const float4*)(arow + k0);
        float4 a1 = *(const float4*)(arow + k0 + 4);
        float xs[8] = {a0.x, a0.y, a0.z, a0.w, a1.x, a1.y, a1.z, a1.w};
        bf16x8 ah, al;
        #pragma unroll
        for (int j = 0; j < 8; ++j) {
            short h, lo2;
            f32_to_bf16_pair(xs[j], h, lo2);
            ah[j] = h; al[j] = lo2;
        }
        #pragma unroll
        for (int nc = 0; nc < 4; ++nc) {
            bf16x8 bhv = *(const bf16x8*)(bh + (size_t)nc * 8192 + k0);
            bf16x8 blv = *(const bf16x8*)(bl + (size_t)nc * 8192 + k0);
            acc[nc] = __builtin_amdgcn_mfma_f32_16x16x32_bf16(ah, bhv, acc[nc], 0, 0, 0);
            acc[nc] = __builtin_amdgcn_mfma_f32_16x16x32_bf16(al, bhv, acc[nc], 0, 0, 0);
            acc[nc] = __builtin_amdgcn_mfma_f32_16x16x32_bf16(ah, blv, acc[nc], 0, 0, 0);
        }
    }

    const float SCL = 2.8853900817779268f;  // 2*log2(e)
    float* cp = C + (size_t)(m0 + w * 16 + lg * 4) * 256 + nt * 64 + lr;
    #pragma unroll
    for (int nc = 0; nc < 4; ++nc)
        #pragma unroll
        for (int r = 0; r < 4; ++r)
            cp[(size_t)r * 256 + nc * 16] = acc[nc][r] * SCL;
}

// ---------------------------------------------------------------------------
// Kernel 2: score partials.  2t x 2s micro-tile + 4-way a-split.
// Grid 2048 = 8b x 4ah x 4tt x 16st, 256 thr.  Block covers 32t x 32s x 64a,
// writes partial S = sum_a V[a]*rcp(1+exp2(w+u)) to plane ah.
// (CV constant dropped: softmax is shift-invariant; ctx folds -2*log2e.)
// ---------------------------------------------------------------------------
__global__ __launch_bounds__(256) void scores_k(
    const float* __restrict__ Whl, const float* __restrict__ Ul,
    const float* __restrict__ Va, float* __restrict__ scoresP)
{
    __shared__ float Ws[32][68];   // bank=(4r+a)%32; lanes r,r+8 collide -> 2-way free
    __shared__ float Us[32][68];
    __shared__ float Vs[64];

    const int bid = blockIdx.x;
    const int b = bid & 7;               // XCD-pinned per batch
    const int rest = bid >> 3;           // 0..255
    const int ah = rest & 3;
    const int tt = (rest >> 2) & 3;
    const int st = rest >> 4;            // 0..15
    const int t0 = tt * 32, s0 = st * 32, a0 = ah * 64;
    const int tid = threadIdx.x;

    if (tid < 64) Vs[tid] = Va[a0 + tid];

    const int r = tid >> 3;              // staging row 0..31
    const int c8 = (tid & 7) * 8;        // staging col octet
    const float* wsrc = Whl + (size_t)(b * 512 + s0 + r) * 256 + a0;
    const float* usrc = Ul + (size_t)(b * 128 + t0 + r) * 256 + a0;
    *(float4*)&Ws[r][c8]     = *(const float4*)&wsrc[c8];
    *(float4*)&Ws[r][c8 + 4] = *(const float4*)&wsrc[c8 + 4];
    *(float4*)&Us[r][c8]     = *(const float4*)&usrc[c8];
    *(float4*)&Us[r][c8 + 4] = *(const float4*)&usrc[c8 + 4];
    __syncthreads();

    const int ts = tid >> 4;             // t row base (broadcast per 16 lanes)
    const int ss = tid & 15;             // s row base (consecutive lanes)
    const float* w0 = Ws[ss];
    const float* w1 = Ws[ss + 16];
    const float* u0 = Us[ts];
    const float* u1 = Us[ts + 16];

    float a00 = 0.f, a01 = 0.f, a10 = 0.f, a11 = 0.f;
    #pragma unroll 4
    for (int a = 0; a < 64; a += 4) {
        float4 wa = *(const float4*)&w0[a];
        float4 wb = *(const float4*)&w1[a];
        float4 ua = *(const float4*)&u0[a];
        float4 ub = *(const float4*)&u1[a];
        float4 v4 = *(const float4*)&Vs[a];
        const float wav[4] = {wa.x, wa.y, wa.z, wa.w};
        const float wbv[4] = {wb.x, wb.y, wb.z, wb.w};
        const float uav[4] = {ua.x, ua.y, ua.z, ua.w};
        const float ubv[4] = {ub.x, ub.y, ub.z, ub.w};
        const float vv[4] = {v4.x, v4.y, v4.z, v4.w};
        #pragma unroll
        for (int q = 0; q < 4; ++q) {
            float r00 = __builtin_amdgcn_rcpf(1.f + __builtin_amdgcn_exp2f(wav[q] + uav[q]));
            float r01 = __builtin_amdgcn_rcpf(1.f + __builtin_amdgcn_exp2f(wbv[q] + uav[q]));
            float r10 = __builtin_amdgcn_rcpf(1.f + __builtin_amdgcn_exp2f(wav[q] + ubv[q]));
            float r11 = __builtin_amdgcn_rcpf(1.f + __builtin_amdgcn_exp2f(wbv[q] + ubv[q]));
            a00 = fmaf(vv[q], r00, a00);
            a01 = fmaf(vv[q], r01, a01);
            a10 = fmaf(vv[q], r10, a10);
            a11 = fmaf(vv[q], r11, a11);
        }
    }

    float* sp = scoresP + (size_t)ah * 524288
              + (size_t)(b * 128 + t0 + ts) * 512 + s0 + ss;
    sp[0]  = a00;
    sp[16] = a01;
    sp += (size_t)16 * 512;
    sp[0]  = a10;
    sp[16] = a11;
}

// ---------------------------------------------------------------------------
// Kernel 3: combine partials + softmax + context.
// Grid 256 = 8b x 32 t-groups(4), 1024 thr (16 waves).  p = softmax(-2*S).
// Ctx: s-split 8 (sh=tid>>7), e4-quad per lane, LDS partial reduce.
// ---------------------------------------------------------------------------
__global__ __launch_bounds__(1024) void softmax_ctx(
    const float* __restrict__ scoresP, const float* __restrict__ values,
    float* __restrict__ out_c, float* __restrict__ out_e)
{
    __shared__ float Ps[4][512];
    __shared__ float Part[7][4][512];

    const int bid = blockIdx.x;
    const int b = bid & 7;
    const int t0 = (bid >> 3) * 4;
    const int tid = threadIdx.x;

    if (tid < 256) {
        const int row = tid >> 6, lane = tid & 63;  // one wave per row
        const float* sp = scoresP + (size_t)(b * 128 + t0 + row) * 512;
        float e[8]; float ssum = 0.f;
        #pragma unroll
        for (int k = 0; k < 8; ++k) {
            const int idx = k * 64 + lane;
            float s = sp[idx] + sp[524288 + idx] + sp[1048576 + idx] + sp[1572864 + idx];
            e[k] = __builtin_amdgcn_exp2f(s * -2.8853900817779268f);  // exp(-2S)
            ssum += e[k];
        }
        #pragma unroll
        for (int off = 32; off > 0; off >>= 1)
            ssum += __shfl_xor(ssum, off);
        const float inv = 1.0f / ssum;
        float* erow = out_e + (size_t)(b * 128 + t0 + row) * 512;
        #pragma unroll
        for (int k = 0; k < 8; ++k) {
            float p = e[k] * inv;
            Ps[row][k * 64 + lane] = p;
            erow[k * 64 + lane] = p;
        }
    }
    __syncthreads();

    const int e4 = (tid & 127) * 4;
    const int sh = tid >> 7;            // 0..7, wave-uniform
    const int sb = sh * 64;
    const float* vb = values + (size_t)b * 262144;

    float4 a0 = {0,0,0,0}, a1 = {0,0,0,0}, a2 = {0,0,0,0}, a3 = {0,0,0,0};
    #pragma unroll 4
    for (int s2 = 0; s2 < 64; ++s2) {
        const int s = sb + s2;
        float4 v4 = *(const float4*)&vb[(size_t)s * 512 + e4];
        float q0 = Ps[0][s], q1 = Ps[1][s], q2 = Ps[2][s], q3 = Ps[3][s];
        a0.x = fmaf(q0, v4.x, a0.x); a0.y = fmaf(q0, v4.y, a0.y);
        a0.z = fmaf(q0, v4.z, a0.z); a0.w = fmaf(q0, v4.w, a0.w);
        a1.x = fmaf(q1, v4.x, a1.x); a1.y = fmaf(q1, v4.y, a1.y);
        a1.z = fmaf(q1, v4.z, a1.z); a1.w = fmaf(q1, v4.w, a1.w);
        a2.x = fmaf(q2, v4.x, a2.x); a2.y = fmaf(q2, v4.y, a2.y);
        a2.z = fmaf(q2, v4.z, a2.z); a2.w = fmaf(q2, v4.w, a2.w);
        a3.x = fmaf(q3, v4.x, a3.x); a3.y = fmaf(q3, v4.y, a3.y);
        a3.z = fmaf(q3, v4.z, a3.z); a3.w = fmaf(q3, v4.w, a3.w);
    }

    if (sh) {
        *(float4*)&Part[sh - 1][0][e4] = a0;
        *(float4*)&Part[sh - 1][1][e4] = a1;
        *(float4*)&Part[sh - 1][2][e4] = a2;
        *(float4*)&Part[sh - 1][3][e4] = a3;
    }
    __syncthreads();
    if (!sh) {
        #pragma unroll
        for (int rrow = 0; rrow < 4; ++rrow) {
            float4 acc = (rrow == 0) ? a0 : (rrow == 1) ? a1 : (rrow == 2) ? a2 : a3;
            #pragma unroll
            for (int g = 0; g < 7; ++g) {
                float4 p4 = *(const float4*)&Part[g][rrow][e4];
                acc.x += p4.x; acc.y += p4.y; acc.z += p4.z; acc.w += p4.w;
            }
            *(float4*)&out_c[(size_t)(b * 128 + t0 + rrow) * 512 + e4] = acc;
        }
    }
}

// ---------------------------------------------------------------------------
extern "C" void kernel_launch(void* const* d_in, const int* in_sizes, int n_in,
                              void* d_out, int out_size, void* d_ws, size_t ws_size,
                              hipStream_t stream) {
    const float* values = (const float*)d_in[0];  // [8,512,512]
    const float* query  = (const float*)d_in[1];  // [8,128,512]
    const float* W_h    = (const float*)d_in[2];  // [512,256]
    const float* U_a    = (const float*)d_in[3];  // [512,256]
    const float* V_a    = (const float*)d_in[4];  // [1,256]

    float* ws      = (float*)d_ws;
    float* Whl     = ws;                           // 4096*256 f32
    float* Ul      = ws + 1048576;                 // 1024*256 f32
    float* scoresP = ws + 1310720;                 // 4 * 524288 f32
    short* WtHi    = (short*)(ws + 3407872);       // 2*256*512 bf16
    short* WtLo    = WtHi + 262144;                // 2*256*512 bf16

    float* out_c = (float*)d_out;                  // [8,128,512]
    float* out_e = out_c + 8 * 128 * 512;          // [8,128,512]

    hipLaunchKernelGGL(prep_w, dim3(64), dim3(256), 0, stream,
                       W_h, U_a, WtHi, WtLo);
    hipLaunchKernelGGL(gemm_mfma, dim3(640), dim3(128), 0, stream,
                       values, query, WtHi, WtLo, Whl, Ul);
    hipLaunchKernelGGL(scores_k, dim3(2048), dim3(256), 0, stream,
                       Whl, Ul, V_a, scoresP);
    hipLaunchKernelGGL(softmax_ctx, dim3(256), dim3(1024), 0, stream,
                       scoresP, values, out_c, out_e);
}

// Round 6
// 69.269 us; speedup vs baseline: 1.4631x; 1.1543x over previous
//
#include <hip/hip_runtime.h>
#include <hip/hip_bf16.h>

// B=8, Te=512, Td=128, D_ENC=D_DEC=512, ATT=256
// A = [values(4096) ; query(1024)] rows, K=512.  W planes = W_h / U_a transposed.
// All MFMA operands stored PRE-SWIZZLED in fragment-linear order:
//   frag(16 rows x 32 k) -> 64 lanes x 8 elems;  offset = frag_id*512 + lane*8 + j
// so every GEMM operand load is a coalesced 1KB wave-load (fixes the 16-way
// cache-line scatter that made round-4/5 gemm TA-bound ~35us).

typedef __attribute__((ext_vector_type(8))) short bf16x8;
typedef __attribute__((ext_vector_type(4))) float f32x4;

__device__ inline void f32_to_bf16_pair(float x, short& h, short& l) {
    unsigned u = __builtin_bit_cast(unsigned, x);
    unsigned r = u + 0x7FFFu + ((u >> 16) & 1u);           // RNE to bf16
    h = (short)(r >> 16);
    float xh = __builtin_bit_cast(float, r & 0xFFFF0000u);
    float xl = x - xh;
    unsigned u2 = __builtin_bit_cast(unsigned, xl);
    unsigned r2 = u2 + 0x7FFFu + ((u2 >> 16) & 1u);
    l = (short)(r2 >> 16);
}

// ---------------------------------------------------------------------------
// Kernel 0a: W_h/U_a -> swizzled B-planes.  Grid 64 = 2mat x 4nb x 8kb, 256thr.
// B-frag elem j of lane (lr=l&15, lg=l>>4) = W[k=ksg*32+lg*8+j][n=ngrp*16+lr].
// Stored at matoff + (ngrp*16 + ksg)*512 + lane*8 + j.
// ---------------------------------------------------------------------------
__global__ __launch_bounds__(256) void prep_w2(
    const float* __restrict__ W_h, const float* __restrict__ U_a,
    short* __restrict__ BHi, short* __restrict__ BLo)
{
    __shared__ float T[64][65];
    const int bid = blockIdx.x;
    const int mat = bid >> 5, nb = (bid >> 3) & 3, kb = bid & 7;
    const float* W = mat ? U_a : W_h;
    const int tid = threadIdx.x;

    {   // stage 64k x 64n tile, coalesced
        const int krow = tid >> 2, cq = (tid & 3) * 16;
        const float* src = W + (size_t)(kb * 64 + krow) * 256 + nb * 64 + cq;
        #pragma unroll
        for (int q = 0; q < 4; ++q)
            *(float4*)&T[krow][cq + q * 4] = *(const float4*)&src[q * 4];
    }
    __syncthreads();
    {   // 8 frags per block; 32 threads per frag; 2 lanes per thread
        const int f = tid >> 5;                 // 0..7
        const int ngl = f >> 1, ksl = f & 1;
        const int l0 = (tid & 31) * 2;
        const int ngrp = nb * 4 + ngl;
        const int ksg = kb * 2 + ksl;
        const size_t base = (size_t)mat * 131072 + ((size_t)(ngrp * 16 + ksg)) * 512;
        #pragma unroll
        for (int li = 0; li < 2; ++li) {
            const int lane = l0 + li;
            const int lr = lane & 15, lg = lane >> 4;
            bf16x8 hv, lv;
            #pragma unroll
            for (int j = 0; j < 8; ++j) {
                short h, l;
                f32_to_bf16_pair(T[ksl * 32 + lg * 8 + j][ngl * 16 + lr], h, l);
                hv[j] = h; lv[j] = l;
            }
            *(bf16x8*)(BHi + base + lane * 8) = hv;
            *(bf16x8*)(BLo + base + lane * 8) = lv;
        }
    }
}

// ---------------------------------------------------------------------------
// Kernel 0b: values/query -> swizzled A-planes.  Grid 320 (one 16-row group
// mg each), 256 thr.  A-frag elem j of lane = A[mg*16+lr][ks*32+lg*8+j],
// stored at (mg*16+ks)*512 + lane*8 + j.  mg 0..255 = values, 256..319 = query.
// ---------------------------------------------------------------------------
__global__ __launch_bounds__(256) void prep_a(
    const float* __restrict__ values, const float* __restrict__ query,
    short* __restrict__ AHi, short* __restrict__ ALo)
{
    __shared__ float T[16][516];
    const int mg = blockIdx.x;
    const float* src = (mg < 256) ? values + (size_t)mg * 16 * 512
                                  : query + (size_t)(mg - 256) * 16 * 512;
    const int tid = threadIdx.x;

    {   // stage 16 rows x 512 k, coalesced
        const int row = tid >> 4, c0 = (tid & 15) * 4;
        #pragma unroll
        for (int i = 0; i < 8; ++i)
            *(float4*)&T[row][c0 + i * 64] = *(const float4*)&src[(size_t)row * 512 + c0 + i * 64];
    }
    __syncthreads();
    {   // thread: frag ks = tid>>4, lanes l4..l4+3
        const int ks = tid >> 4;
        const int l4 = (tid & 15) * 4;
        const size_t base = ((size_t)(mg * 16 + ks)) * 512;
        #pragma unroll
        for (int li = 0; li < 4; ++li) {
            const int lane = l4 + li;
            const int lr = lane & 15, lg = lane >> 4;
            bf16x8 hv, lv;
            #pragma unroll
            for (int j = 0; j < 8; ++j) {
                short h, l;
                f32_to_bf16_pair(T[lr][ks * 32 + lg * 8 + j], h, l);
                hv[j] = h; lv[j] = l;
            }
            *(bf16x8*)(AHi + base + lane * 8) = hv;
            *(bf16x8*)(ALo + base + lane * 8) = lv;
        }
    }
}

// ---------------------------------------------------------------------------
// Kernel 1: MFMA split-bf16 GEMM (3-pass), all operands swizzled-coalesced.
// Grid 640 = 160 mt(32 rows) x 4 nt(64 cols), 128 thr = 2 waves.
// ---------------------------------------------------------------------------
__global__ __launch_bounds__(128) void gemm_mfma(
    const short* __restrict__ AHi, const short* __restrict__ ALo,
    const short* __restrict__ BHi, const short* __restrict__ BLo,
    float* __restrict__ WhO, float* __restrict__ UO)
{
    const int bid = blockIdx.x;
    const int mt = bid >> 2, nt = bid & 3;
    const int tid = threadIdx.x;
    const int w = tid >> 6, l = tid & 63;
    const int lr = l & 15, lg = l >> 4;

    float* C; int m0, mg, matoff;
    if (mt < 128) { C = WhO; m0 = mt * 32; mg = mt * 2 + w; matoff = 0; }
    else { C = UO; m0 = (mt - 128) * 32; mg = 256 + (mt - 128) * 2 + w; matoff = 131072; }

    const short* ah_p = AHi + ((size_t)mg * 16) * 512 + l * 8;
    const short* al_p = ALo + ((size_t)mg * 16) * 512 + l * 8;
    const short* bh_p = BHi + matoff + ((size_t)(nt * 4) * 16) * 512 + l * 8;
    const short* bl_p = BLo + matoff + ((size_t)(nt * 4) * 16) * 512 + l * 8;

    f32x4 acc[4];
    #pragma unroll
    for (int nc = 0; nc < 4; ++nc) acc[nc] = (f32x4){0.f, 0.f, 0.f, 0.f};

    #pragma unroll 2
    for (int ks = 0; ks < 16; ++ks) {
        bf16x8 ah = *(const bf16x8*)(ah_p + (size_t)ks * 512);
        bf16x8 al = *(const bf16x8*)(al_p + (size_t)ks * 512);
        #pragma unroll
        for (int nc = 0; nc < 4; ++nc) {
            bf16x8 bh = *(const bf16x8*)(bh_p + ((size_t)(nc * 16 + ks)) * 512);
            bf16x8 bl = *(const bf16x8*)(bl_p + ((size_t)(nc * 16 + ks)) * 512);
            acc[nc] = __builtin_amdgcn_mfma_f32_16x16x32_bf16(ah, bh, acc[nc], 0, 0, 0);
            acc[nc] = __builtin_amdgcn_mfma_f32_16x16x32_bf16(al, bh, acc[nc], 0, 0, 0);
            acc[nc] = __builtin_amdgcn_mfma_f32_16x16x32_bf16(ah, bl, acc[nc], 0, 0, 0);
        }
    }

    const float SCL = 2.8853900817779268f;  // 2*log2(e)
    float* cp = C + (size_t)(m0 + w * 16 + lg * 4) * 256 + nt * 64 + lr;
    #pragma unroll
    for (int nc = 0; nc < 4; ++nc)
        #pragma unroll
        for (int r = 0; r < 4; ++r)
            cp[(size_t)r * 256 + nc * 16] = acc[nc][r] * SCL;
}

// ---------------------------------------------------------------------------
// Kernel 2: score partials, 2t x 4s micro-tile, 4-way a-split.
// Grid 1024 = 8b x 4ah x 4tt x 8st, 256 thr.  Block = 32t x 64s x 64a.
// partial S = sum_a V[a]*rcp(1+exp2(w+u)); p = softmax(-2S) downstream.
// V read via wave-uniform scalar loads (no LDS).
// ---------------------------------------------------------------------------
__global__ __launch_bounds__(256) void scores_k(
    const float* __restrict__ Whl, const float* __restrict__ Ul,
    const float* __restrict__ Va, float* __restrict__ scoresP)
{
    __shared__ float Ws[64][68];
    __shared__ float Us[32][68];

    const int bid = blockIdx.x;
    const int b = bid & 7;               // XCD-pinned per batch
    const int rest = bid >> 3;           // 0..127
    const int ah = rest & 3;
    const int tt = (rest >> 2) & 3;
    const int st = rest >> 4;            // 0..7
    const int t0 = tt * 32, s0 = st * 64, a0 = ah * 64;
    const int tid = threadIdx.x;

    {   // stage W rows (64 x 64) and U rows (32 x 64)
        const int r = tid >> 2, c16 = (tid & 3) * 16;
        const float* wsrc = Whl + (size_t)(b * 512 + s0 + r) * 256 + a0 + c16;
        #pragma unroll
        for (int q = 0; q < 4; ++q)
            *(float4*)&Ws[r][c16 + q * 4] = *(const float4*)&wsrc[q * 4];
        const int r8 = tid >> 3, c8 = (tid & 7) * 8;
        const float* usrc = Ul + (size_t)(b * 128 + t0 + r8) * 256 + a0 + c8;
        *(float4*)&Us[r8][c8]     = *(const float4*)&usrc[0];
        *(float4*)&Us[r8][c8 + 4] = *(const float4*)&usrc[4];
    }
    __syncthreads();

    const int ts = tid >> 4;             // t rows {ts, ts+16}
    const int ss = tid & 15;             // s rows {ss, ss+16, ss+32, ss+48}
    const float* Vp = Va + a0;

    float acc[2][4] = {};
    #pragma unroll 2
    for (int a = 0; a < 64; a += 4) {
        float4 u0 = *(const float4*)&Us[ts][a];
        float4 u1 = *(const float4*)&Us[ts + 16][a];
        float4 w0 = *(const float4*)&Ws[ss][a];
        float4 w1 = *(const float4*)&Ws[ss + 16][a];
        float4 w2 = *(const float4*)&Ws[ss + 32][a];
        float4 w3 = *(const float4*)&Ws[ss + 48][a];
        const float uv[2][4] = {{u0.x, u0.y, u0.z, u0.w}, {u1.x, u1.y, u1.z, u1.w}};
        const float wv[4][4] = {{w0.x, w0.y, w0.z, w0.w}, {w1.x, w1.y, w1.z, w1.w},
                                {w2.x, w2.y, w2.z, w2.w}, {w3.x, w3.y, w3.z, w3.w}};
        #pragma unroll
        for (int q = 0; q < 4; ++q) {
            const float vq = Vp[a + q];     // wave-uniform -> scalar load
            #pragma unroll
            for (int i = 0; i < 2; ++i)
                #pragma unroll
                for (int k = 0; k < 4; ++k) {
                    float e = __builtin_amdgcn_exp2f(wv[k][q] + uv[i][q]);
                    float r = __builtin_amdgcn_rcpf(1.f + e);
                    acc[i][k] = fmaf(vq, r, acc[i][k]);
                }
        }
    }

    float* sp = scoresP + (size_t)ah * 524288
              + (size_t)(b * 128 + t0 + ts) * 512 + s0 + ss;
    #pragma unroll
    for (int k = 0; k < 4; ++k) sp[k * 16] = acc[0][k];
    sp += (size_t)16 * 512;
    #pragma unroll
    for (int k = 0; k < 4; ++k) sp[k * 16] = acc[1][k];
}

// ---------------------------------------------------------------------------
// Kernel 3: combine partials + softmax + context.
// Grid 256 = 8b x 32 t-groups(4), 1024 thr.  p = softmax(-2*S).
// Ctx: 8-way s-split, float4 Ps reads, LDS partial reduce.
// ---------------------------------------------------------------------------
__global__ __launch_bounds__(1024) void softmax_ctx(
    const float* __restrict__ scoresP, const float* __restrict__ values,
    float* __restrict__ out_c, float* __restrict__ out_e)
{
    __shared__ float Ps[4][512];
    __shared__ float Part[7][4][512];

    const int bid = blockIdx.x;
    const int b = bid & 7;
    const int t0 = (bid >> 3) * 4;
    const int tid = threadIdx.x;

    if (tid < 256) {
        const int row = tid >> 6, lane = tid & 63;  // one wave per row
        const float* sp = scoresP + (size_t)(b * 128 + t0 + row) * 512;
        float e[8]; float ssum = 0.f;
        #pragma unroll
        for (int k = 0; k < 8; ++k) {
            const int idx = k * 64 + lane;
            float s = sp[idx] + sp[524288 + idx] + sp[1048576 + idx] + sp[1572864 + idx];
            e[k] = __builtin_amdgcn_exp2f(s * -2.8853900817779268f);  // exp(-2S)
            ssum += e[k];
        }
        #pragma unroll
        for (int off = 32; off > 0; off >>= 1)
            ssum += __shfl_xor(ssum, off);
        const float inv = 1.0f / ssum;
        float* erow = out_e + (size_t)(b * 128 + t0 + row) * 512;
        #pragma unroll
        for (int k = 0; k < 8; ++k) {
            float p = e[k] * inv;
            Ps[row][k * 64 + lane] = p;
            erow[k * 64 + lane] = p;
        }
    }
    __syncthreads();

    const int e4 = (tid & 127) * 4;
    const int sh = tid >> 7;            // 0..7, wave-uniform
    const int sb = sh * 64;
    const float* vb = values + (size_t)b * 262144;

    float4 a0 = {0,0,0,0}, a1 = {0,0,0,0}, a2 = {0,0,0,0}, a3 = {0,0,0,0};
    #pragma unroll 2
    for (int s2 = 0; s2 < 64; s2 += 4) {
        float4 q0 = *(const float4*)&Ps[0][sb + s2];
        float4 q1 = *(const float4*)&Ps[1][sb + s2];
        float4 q2 = *(const float4*)&Ps[2][sb + s2];
        float4 q3 = *(const float4*)&Ps[3][sb + s2];
        const float q0v[4] = {q0.x, q0.y, q0.z, q0.w};
        const float q1v[4] = {q1.x, q1.y, q1.z, q1.w};
        const float q2v[4] = {q2.x, q2.y, q2.z, q2.w};
        const float q3v[4] = {q3.x, q3.y, q3.z, q3.w};
        #pragma unroll
        for (int j = 0; j < 4; ++j) {
            float4 v4 = *(const float4*)&vb[(size_t)(sb + s2 + j) * 512 + e4];
            a0.x = fmaf(q0v[j], v4.x, a0.x); a0.y = fmaf(q0v[j], v4.y, a0.y);
            a0.z = fmaf(q0v[j], v4.z, a0.z); a0.w = fmaf(q0v[j], v4.w, a0.w);
            a1.x = fmaf(q1v[j], v4.x, a1.x); a1.y = fmaf(q1v[j], v4.y, a1.y);
            a1.z = fmaf(q1v[j], v4.z, a1.z); a1.w = fmaf(q1v[j], v4.w, a1.w);
            a2.x = fmaf(q2v[j], v4.x, a2.x); a2.y = fmaf(q2v[j], v4.y, a2.y);
            a2.z = fmaf(q2v[j], v4.z, a2.z); a2.w = fmaf(q2v[j], v4.w, a2.w);
            a3.x = fmaf(q3v[j], v4.x, a3.x); a3.y = fmaf(q3v[j], v4.y, a3.y);
            a3.z = fmaf(q3v[j], v4.z, a3.z); a3.w = fmaf(q3v[j], v4.w, a3.w);
        }
    }

    if (sh) {
        *(float4*)&Part[sh - 1][0][e4] = a0;
        *(float4*)&Part[sh - 1][1][e4] = a1;
        *(float4*)&Part[sh - 1][2][e4] = a2;
        *(float4*)&Part[sh - 1][3][e4] = a3;
    }
    __syncthreads();
    if (!sh) {
        #pragma unroll
        for (int rrow = 0; rrow < 4; ++rrow) {
            float4 acc = (rrow == 0) ? a0 : (rrow == 1) ? a1 : (rrow == 2) ? a2 : a3;
            #pragma unroll
            for (int g = 0; g < 7; ++g) {
                float4 p4 = *(const float4*)&Part[g][rrow][e4];
                acc.x += p4.x; acc.y += p4.y; acc.z += p4.z; acc.w += p4.w;
            }
            *(float4*)&out_c[(size_t)(b * 128 + t0 + rrow) * 512 + e4] = acc;
        }
    }
}

// ---------------------------------------------------------------------------
extern "C" void kernel_launch(void* const* d_in, const int* in_sizes, int n_in,
                              void* d_out, int out_size, void* d_ws, size_t ws_size,
                              hipStream_t stream) {
    const float* values = (const float*)d_in[0];  // [8,512,512]
    const float* query  = (const float*)d_in[1];  // [8,128,512]
    const float* W_h    = (const float*)d_in[2];  // [512,256]
    const float* U_a    = (const float*)d_in[3];  // [512,256]
    const float* V_a    = (const float*)d_in[4];  // [1,256]

    float* ws      = (float*)d_ws;
    float* Whl     = ws;                           // 4096*256 f32
    float* Ul      = ws + 1048576;                 // 1024*256 f32
    float* scoresP = ws + 1310720;                 // 4 * 524288 f32
    short* S       = (short*)(ws + 3407872);
    short* AHi     = S;                            // 5120*512 bf16
    short* ALo     = S + 2621440;
    short* BHi     = S + 5242880;                  // 2*256*512 bf16
    short* BLo     = S + 5505024;

    float* out_c = (float*)d_out;                  // [8,128,512]
    float* out_e = out_c + 8 * 128 * 512;          // [8,128,512]

    hipLaunchKernelGGL(prep_w2, dim3(64), dim3(256), 0, stream,
                       W_h, U_a, BHi, BLo);
    hipLaunchKernelGGL(prep_a, dim3(320), dim3(256), 0, stream,
                       values, query, AHi, ALo);
    hipLaunchKernelGGL(gemm_mfma, dim3(640), dim3(128), 0, stream,
                       AHi, ALo, BHi, BLo, Whl, Ul);
    hipLaunchKernelGGL(scores_k, dim3(1024), dim3(256), 0, stream,
                       Whl, Ul, V_a, scoresP);
    hipLaunchKernelGGL(softmax_ctx, dim3(256), dim3(1024), 0, stream,
                       scoresP, values, out_c, out_e);
}

// Round 7
// 64.763 us; speedup vs baseline: 1.5649x; 1.0696x over previous
//
#include <hip/hip_runtime.h>
#include <hip/hip_bf16.h>

// B=8, Te=512, Td=128, D_ENC=D_DEC=512, ATT=256
// ws: Whl [4096,256] f32 (scaled 2*log2e), Ul [1024,256] f32, scoresP 4 planes,
//     AHi/ALo [5120*512] bf16 frag-swizzled, BHi/BLo [2*256*512] bf16 frag-swizzled.
// Fragment-linear layout: frag(16 rows x 32 k) -> offset = frag_id*512 + lane*8 + j.

typedef __attribute__((ext_vector_type(8))) short bf16x8;
typedef __attribute__((ext_vector_type(4))) float f32x4;

__device__ inline void f32_to_bf16_pair(float x, short& h, short& l) {
    unsigned u = __builtin_bit_cast(unsigned, x);
    unsigned r = u + 0x7FFFu + ((u >> 16) & 1u);           // RNE to bf16
    h = (short)(r >> 16);
    float xh = __builtin_bit_cast(float, r & 0xFFFF0000u);
    float xl = x - xh;
    unsigned u2 = __builtin_bit_cast(unsigned, xl);
    unsigned r2 = u2 + 0x7FFFu + ((u2 >> 16) & 1u);
    l = (short)(r2 >> 16);
}

// ---------------------------------------------------------------------------
// Kernel 0: merged prep.  bid<64: W_h/U_a -> swizzled B planes (2mat x 4nb x 8kb).
// bid>=64: values/query -> swizzled A planes (mg = bid-64, 0..319).
// ---------------------------------------------------------------------------
__global__ __launch_bounds__(256) void prep(
    const float* __restrict__ W_h, const float* __restrict__ U_a,
    const float* __restrict__ values, const float* __restrict__ query,
    short* __restrict__ BHi, short* __restrict__ BLo,
    short* __restrict__ AHi, short* __restrict__ ALo)
{
    __shared__ float TW[64][65];
    __shared__ float TA[16][516];
    const int bid = blockIdx.x;
    const int tid = threadIdx.x;

    if (bid < 64) {
        const int mat = bid >> 5, nb = (bid >> 3) & 3, kb = bid & 7;
        const float* W = mat ? U_a : W_h;
        {   // stage 64k x 64n tile, coalesced
            const int krow = tid >> 2, cq = (tid & 3) * 16;
            const float* src = W + (size_t)(kb * 64 + krow) * 256 + nb * 64 + cq;
            #pragma unroll
            for (int q = 0; q < 4; ++q)
                *(float4*)&TW[krow][cq + q * 4] = *(const float4*)&src[q * 4];
        }
        __syncthreads();
        {   // 8 frags per block; 32 threads per frag; 2 lanes per thread
            const int f = tid >> 5;
            const int ngl = f >> 1, ksl = f & 1;
            const int l0 = (tid & 31) * 2;
            const int ngrp = nb * 4 + ngl;
            const int ksg = kb * 2 + ksl;
            const size_t base = (size_t)mat * 131072 + ((size_t)(ngrp * 16 + ksg)) * 512;
            #pragma unroll
            for (int li = 0; li < 2; ++li) {
                const int lane = l0 + li;
                const int lr = lane & 15, lg = lane >> 4;
                bf16x8 hv, lv;
                #pragma unroll
                for (int j = 0; j < 8; ++j) {
                    short h, l;
                    f32_to_bf16_pair(TW[ksl * 32 + lg * 8 + j][ngl * 16 + lr], h, l);
                    hv[j] = h; lv[j] = l;
                }
                *(bf16x8*)(BHi + base + lane * 8) = hv;
                *(bf16x8*)(BLo + base + lane * 8) = lv;
            }
        }
    } else {
        const int mg = bid - 64;
        const float* src = (mg < 256) ? values + (size_t)mg * 16 * 512
                                      : query + (size_t)(mg - 256) * 16 * 512;
        {   // stage 16 rows x 512 k, coalesced
            const int row = tid >> 4, c0 = (tid & 15) * 4;
            #pragma unroll
            for (int i = 0; i < 8; ++i)
                *(float4*)&TA[row][c0 + i * 64] =
                    *(const float4*)&src[(size_t)row * 512 + c0 + i * 64];
        }
        __syncthreads();
        {   // frag ks = tid>>4, lanes l4..l4+3
            const int ks = tid >> 4;
            const int l4 = (tid & 15) * 4;
            const size_t base = ((size_t)(mg * 16 + ks)) * 512;
            #pragma unroll
            for (int li = 0; li < 4; ++li) {
                const int lane = l4 + li;
                const int lr = lane & 15, lg = lane >> 4;
                bf16x8 hv, lv;
                #pragma unroll
                for (int j = 0; j < 8; ++j) {
                    short h, l;
                    f32_to_bf16_pair(TA[lr][ks * 32 + lg * 8 + j], h, l);
                    hv[j] = h; lv[j] = l;
                }
                *(bf16x8*)(AHi + base + lane * 8) = hv;
                *(bf16x8*)(ALo + base + lane * 8) = lv;
            }
        }
    }
}

// ---------------------------------------------------------------------------
// Kernel 1: MFMA split-bf16 GEMM (3-pass), swizzled-coalesced operands.
// Grid 640 = 160 mt(32 rows) x 4 nt(64 cols), 128 thr = 2 waves.
// ---------------------------------------------------------------------------
__global__ __launch_bounds__(128) void gemm_mfma(
    const short* __restrict__ AHi, const short* __restrict__ ALo,
    const short* __restrict__ BHi, const short* __restrict__ BLo,
    float* __restrict__ WhO, float* __restrict__ UO)
{
    const int bid = blockIdx.x;
    const int mt = bid >> 2, nt = bid & 3;
    const int tid = threadIdx.x;
    const int w = tid >> 6, l = tid & 63;
    const int lr = l & 15, lg = l >> 4;

    float* C; int m0, mg, matoff;
    if (mt < 128) { C = WhO; m0 = mt * 32; mg = mt * 2 + w; matoff = 0; }
    else { C = UO; m0 = (mt - 128) * 32; mg = 256 + (mt - 128) * 2 + w; matoff = 131072; }

    const short* ah_p = AHi + ((size_t)mg * 16) * 512 + l * 8;
    const short* al_p = ALo + ((size_t)mg * 16) * 512 + l * 8;
    const short* bh_p = BHi + matoff + ((size_t)(nt * 4) * 16) * 512 + l * 8;
    const short* bl_p = BLo + matoff + ((size_t)(nt * 4) * 16) * 512 + l * 8;

    f32x4 acc[4];
    #pragma unroll
    for (int nc = 0; nc < 4; ++nc) acc[nc] = (f32x4){0.f, 0.f, 0.f, 0.f};

    #pragma unroll 2
    for (int ks = 0; ks < 16; ++ks) {
        bf16x8 ah = *(const bf16x8*)(ah_p + (size_t)ks * 512);
        bf16x8 al = *(const bf16x8*)(al_p + (size_t)ks * 512);
        #pragma unroll
        for (int nc = 0; nc < 4; ++nc) {
            bf16x8 bh = *(const bf16x8*)(bh_p + ((size_t)(nc * 16 + ks)) * 512);
            bf16x8 bl = *(const bf16x8*)(bl_p + ((size_t)(nc * 16 + ks)) * 512);
            acc[nc] = __builtin_amdgcn_mfma_f32_16x16x32_bf16(ah, bh, acc[nc], 0, 0, 0);
            acc[nc] = __builtin_amdgcn_mfma_f32_16x16x32_bf16(al, bh, acc[nc], 0, 0, 0);
            acc[nc] = __builtin_amdgcn_mfma_f32_16x16x32_bf16(ah, bl, acc[nc], 0, 0, 0);
        }
    }

    const float SCL = 2.8853900817779268f;  // 2*log2(e)
    float* cp = C + (size_t)(m0 + w * 16 + lg * 4) * 256 + nt * 64 + lr;
    #pragma unroll
    for (int nc = 0; nc < 4; ++nc)
        #pragma unroll
        for (int r = 0; r < 4; ++r)
            cp[(size_t)r * 256 + nc * 16] = acc[nc][r] * SCL;
}

// ---------------------------------------------------------------------------
// Kernel 2: score partials, 1t x 4s per thread, 4-way a-split.
// Grid 2048 = 8b x 4ah x 8tt x 8st, 256 thr.  Block = 16t x 64s x 64a.
// 8 blocks/CU capable (LDS 22KB) -> 100% occupancy.
// partial S = sum_a V[a]*rcp(1+exp2(w+u)); p = softmax(-2S) downstream.
// ---------------------------------------------------------------------------
__global__ __launch_bounds__(256) void scores_k(
    const float* __restrict__ Whl, const float* __restrict__ Ul,
    const float* __restrict__ Va, float* __restrict__ scoresP)
{
    __shared__ float Ws[64][68];   // bank=(4r+a)%32 -> 2-way on b128 reads (free)
    __shared__ float Us[16][68];

    const int bid = blockIdx.x;
    const int b = bid & 7;               // XCD-pinned per batch
    const int rest = bid >> 3;           // 0..255
    const int ah = rest & 3;
    const int tt = (rest >> 2) & 7;      // 8 t-tiles of 16
    const int st = rest >> 5;            // 8 s-tiles of 64
    const int t0 = tt * 16, s0 = st * 64, a0 = ah * 64;
    const int tid = threadIdx.x;

    {   // stage W (64s x 64a) and U (16t x 64a)
        const int r = tid >> 2, c16 = (tid & 3) * 16;
        const float* wsrc = Whl + (size_t)(b * 512 + s0 + r) * 256 + a0 + c16;
        #pragma unroll
        for (int q = 0; q < 4; ++q)
            *(float4*)&Ws[r][c16 + q * 4] = *(const float4*)&wsrc[q * 4];
        const int r8 = tid >> 4, c8 = (tid & 15) * 4;
        const float* usrc = Ul + (size_t)(b * 128 + t0 + r8) * 256 + a0 + c8;
        *(float4*)&Us[r8][c8] = *(const float4*)&usrc[0];
    }
    __syncthreads();

    const int t = tid >> 4;              // 0..15 (broadcast per 16 lanes)
    const int ss = tid & 15;             // s rows {ss, ss+16, ss+32, ss+48}
    const float* Vp = Va + a0;

    float acc[4] = {};
    #pragma unroll 4
    for (int a = 0; a < 64; a += 4) {
        float4 u  = *(const float4*)&Us[t][a];
        float4 w0 = *(const float4*)&Ws[ss][a];
        float4 w1 = *(const float4*)&Ws[ss + 16][a];
        float4 w2 = *(const float4*)&Ws[ss + 32][a];
        float4 w3 = *(const float4*)&Ws[ss + 48][a];
        const float uv[4] = {u.x, u.y, u.z, u.w};
        const float wv[4][4] = {{w0.x, w0.y, w0.z, w0.w}, {w1.x, w1.y, w1.z, w1.w},
                                {w2.x, w2.y, w2.z, w2.w}, {w3.x, w3.y, w3.z, w3.w}};
        #pragma unroll
        for (int q = 0; q < 4; ++q) {
            const float vq = Vp[a + q];  // wave-uniform -> scalar load
            #pragma unroll
            for (int k = 0; k < 4; ++k) {
                float e = __builtin_amdgcn_exp2f(wv[k][q] + uv[q]);
                float r = __builtin_amdgcn_rcpf(1.f + e);
                acc[k] = fmaf(vq, r, acc[k]);
            }
        }
    }

    float* sp = scoresP + (size_t)ah * 524288
              + (size_t)(b * 128 + t0 + t) * 512 + s0 + ss;
    #pragma unroll
    for (int k = 0; k < 4; ++k) sp[k * 16] = acc[k];
}

// ---------------------------------------------------------------------------
// Kernel 3: combine partials + softmax + context, e-split 2.
// Grid 512 = 8b x 32 tg(4t) x 2 eh, 512 thr.  p = softmax(-2*S).
// Ctx: 8-way s-split (sh=tid>>6), 256-wide e half, LDS partial reduce.
// ---------------------------------------------------------------------------
__global__ __launch_bounds__(512) void softmax_ctx(
    const float* __restrict__ scoresP, const float* __restrict__ values,
    float* __restrict__ out_c, float* __restrict__ out_e)
{
    __shared__ float Ps[4][512];
    __shared__ float Part[7][4][256];

    const int bid = blockIdx.x;
    const int b = bid & 7;
    const int rest = bid >> 3;          // 0..63
    const int tg = rest & 31;
    const int eh = rest >> 5;           // 0..1
    const int t0 = tg * 4;
    const int tid = threadIdx.x;

    if (tid < 256) {
        const int row = tid >> 6, lane = tid & 63;  // one wave per row
        const float* sp = scoresP + (size_t)(b * 128 + t0 + row) * 512;
        float e[8]; float ssum = 0.f;
        #pragma unroll
        for (int k = 0; k < 8; ++k) {
            const int idx = k * 64 + lane;
            float s = sp[idx] + sp[524288 + idx] + sp[1048576 + idx] + sp[1572864 + idx];
            e[k] = __builtin_amdgcn_exp2f(s * -2.8853900817779268f);  // exp(-2S)
            ssum += e[k];
        }
        #pragma unroll
        for (int off = 32; off > 0; off >>= 1)
            ssum += __shfl_xor(ssum, off);
        const float inv = 1.0f / ssum;
        float* erow = out_e + (size_t)(b * 128 + t0 + row) * 512;
        #pragma unroll
        for (int k = 0; k < 8; ++k) {
            float p = e[k] * inv;
            Ps[row][k * 64 + lane] = p;
            if (eh == 0) erow[k * 64 + lane] = p;   // only one e-half writes out_e
        }
    }
    __syncthreads();

    const int el = (tid & 63) * 4;            // 0..252 within half
    const int e4 = eh * 256 + el;             // global e
    const int sh = tid >> 6;                  // 0..7, wave-uniform
    const int sb = sh * 64;
    const float* vb = values + (size_t)b * 262144;

    float4 a0 = {0,0,0,0}, a1 = {0,0,0,0}, a2 = {0,0,0,0}, a3 = {0,0,0,0};
    #pragma unroll 2
    for (int s2 = 0; s2 < 64; s2 += 4) {
        float4 q0 = *(const float4*)&Ps[0][sb + s2];
        float4 q1 = *(const float4*)&Ps[1][sb + s2];
        float4 q2 = *(const float4*)&Ps[2][sb + s2];
        float4 q3 = *(const float4*)&Ps[3][sb + s2];
        const float q0v[4] = {q0.x, q0.y, q0.z, q0.w};
        const float q1v[4] = {q1.x, q1.y, q1.z, q1.w};
        const float q2v[4] = {q2.x, q2.y, q2.z, q2.w};
        const float q3v[4] = {q3.x, q3.y, q3.z, q3.w};
        #pragma unroll
        for (int j = 0; j < 4; ++j) {
            float4 v4 = *(const float4*)&vb[(size_t)(sb + s2 + j) * 512 + e4];
            a0.x = fmaf(q0v[j], v4.x, a0.x); a0.y = fmaf(q0v[j], v4.y, a0.y);
            a0.z = fmaf(q0v[j], v4.z, a0.z); a0.w = fmaf(q0v[j], v4.w, a0.w);
            a1.x = fmaf(q1v[j], v4.x, a1.x); a1.y = fmaf(q1v[j], v4.y, a1.y);
            a1.z = fmaf(q1v[j], v4.z, a1.z); a1.w = fmaf(q1v[j], v4.w, a1.w);
            a2.x = fmaf(q2v[j], v4.x, a2.x); a2.y = fmaf(q2v[j], v4.y, a2.y);
            a2.z = fmaf(q2v[j], v4.z, a2.z); a2.w = fmaf(q2v[j], v4.w, a2.w);
            a3.x = fmaf(q3v[j], v4.x, a3.x); a3.y = fmaf(q3v[j], v4.y, a3.y);
            a3.z = fmaf(q3v[j], v4.z, a3.z); a3.w = fmaf(q3v[j], v4.w, a3.w);
        }
    }

    if (sh) {
        *(float4*)&Part[sh - 1][0][el] = a0;
        *(float4*)&Part[sh - 1][1][el] = a1;
        *(float4*)&Part[sh - 1][2][el] = a2;
        *(float4*)&Part[sh - 1][3][el] = a3;
    }
    __syncthreads();
    if (!sh) {
        #pragma unroll
        for (int rrow = 0; rrow < 4; ++rrow) {
            float4 acc = (rrow == 0) ? a0 : (rrow == 1) ? a1 : (rrow == 2) ? a2 : a3;
            #pragma unroll
            for (int g = 0; g < 7; ++g) {
                float4 p4 = *(const float4*)&Part[g][rrow][el];
                acc.x += p4.x; acc.y += p4.y; acc.z += p4.z; acc.w += p4.w;
            }
            *(float4*)&out_c[(size_t)(b * 128 + t0 + rrow) * 512 + e4] = acc;
        }
    }
}

// ---------------------------------------------------------------------------
extern "C" void kernel_launch(void* const* d_in, const int* in_sizes, int n_in,
                              void* d_out, int out_size, void* d_ws, size_t ws_size,
                              hipStream_t stream) {
    const float* values = (const float*)d_in[0];  // [8,512,512]
    const float* query  = (const float*)d_in[1];  // [8,128,512]
    const float* W_h    = (const float*)d_in[2];  // [512,256]
    const float* U_a    = (const float*)d_in[3];  // [512,256]
    const float* V_a    = (const float*)d_in[4];  // [1,256]

    float* ws      = (float*)d_ws;
    float* Whl     = ws;                           // 4096*256 f32
    float* Ul      = ws + 1048576;                 // 1024*256 f32
    float* scoresP = ws + 1310720;                 // 4 * 524288 f32
    short* S       = (short*)(ws + 3407872);
    short* AHi     = S;                            // 5120*512 bf16
    short* ALo     = S + 2621440;
    short* BHi     = S + 5242880;                  // 2*256*512 bf16
    short* BLo     = S + 5505024;

    float* out_c = (float*)d_out;                  // [8,128,512]
    float* out_e = out_c + 8 * 128 * 512;          // [8,128,512]

    hipLaunchKernelGGL(prep, dim3(384), dim3(256), 0, stream,
                       W_h, U_a, values, query, BHi, BLo, AHi, ALo);
    hipLaunchKernelGGL(gemm_mfma, dim3(640), dim3(128), 0, stream,
                       AHi, ALo, BHi, BLo, Whl, Ul);
    hipLaunchKernelGGL(scores_k, dim3(2048), dim3(256), 0, stream,
                       Whl, Ul, V_a, scoresP);
    hipLaunchKernelGGL(softmax_ctx, dim3(512), dim3(512), 0, stream,
                       scoresP, values, out_c, out_e);
}